// Round 9
// baseline (58.245 us; speedup 1.0000x reference)
//
#include <hip/hip_runtime.h>
#include <hip/hip_bf16.h>

// BinaryReflectanceGate: pointwise MLP (4->16->16, relu) -> segment max over
// sorted batch ids [B=64] -> 2-logit gate + gumbel softmax -> scale reflectance.
//
// Round-9: register-direct kernel A (no LDS staging, no hot-loop barriers).
//   Insight: the point->MFMA-column mapping is arbitrary (segmax reduces over
//   all columns). Let lane l own points 4l..4l+3: its pos floats 12l..12l+11
//   are exactly 3 aligned float4s (+1 refl float4) -> point-major in registers
//   directly from coalesced-ish loads. In MFMA (j,t), lanes with g==t feed
//   their j-th point; column c's point id = sb + 4*(16t+c) + j (closed form,
//   used for straddle select). 2048 blocks x 4 waves x 512 pts; all loads of
//   a wave-iteration issued up front for memory-level parallelism.
//
// MFMA layout facts (HW-verified r4, absmax 0.0039):
//   C/D: col=lane&15, row=(lane>>4)*4+reg. A lane(g,c) holds A[row=c][k=4g+e];
//   B lane(g,c) holds B[k=4g+e][col=c]. Layer-1 D fragment IS the layer-2 B
//   fragment under the same k-map.

#define N_PTS 4194304
#define NB 64
#define NH 16
#define WPB 4                       // waves per block
#define SITERS 2                    // 256-pt iterations per wave
#define PTW (256 * SITERS)          // 512 points per wave
#define PPB (WPB * PTW)             // 2048 points per block
#define NBLK (N_PTS / PPB)          // 2048 blocks
#define NENT (NBLK * 2)             // 4096 partial entries

typedef __attribute__((ext_vector_type(8))) short bf16x8;
typedef __attribute__((ext_vector_type(4))) float f32x4;
union U8 { bf16x8 v; unsigned u[4]; unsigned short s[8]; };

struct Rec { int idA, idB, bpos; };

__device__ __forceinline__ unsigned pk2(float a, float b) {
    float2 t; t.x = a; t.y = b;
    __hip_bfloat162 r = __float22bfloat162_rn(t);
    unsigned u;
    __builtin_memcpy(&u, &r, sizeof(u));
    return u;
}
__device__ __forceinline__ unsigned short f2bf(float x) {   // RNE, setup only
    unsigned u = __float_as_uint(x);
    u = u + 0x7fffu + ((u >> 16) & 1u);
    return (unsigned short)(u >> 16);
}

// ---------------- A: MLP + segment-max partials + records ----------------
__global__ __launch_bounds__(256) void mlp_segmax_kernel(
    const float* __restrict__ pos,    // [N,3]
    const float* __restrict__ refl,   // [N]
    const int*   __restrict__ batch,  // [N] sorted
    const float* __restrict__ W1, const float* __restrict__ b1,
    const float* __restrict__ W2, const float* __restrict__ b2,
    float* __restrict__ pv,           // [NENT,16]
    int*   __restrict__ pid,          // [NENT]
    Rec*   __restrict__ recs)         // [NBLK]
{
    __shared__ float lv[WPB][2][NH];
    __shared__ int   li[WPB][2];
    __shared__ int   lbp[WPB];

    const int lane = threadIdx.x & 63;
    const int wid  = threadIdx.x >> 6;
    const int col  = lane & 15;
    const int g    = lane >> 4;
    const int wb   = (blockIdx.x * WPB + wid) * PTW;

    // weight / bias fragments (L1-cached one-time loads)
    U8 A1, A2;
#pragma unroll
    for (int e = 0; e < 4; ++e) {
        A1.s[e]     = f2bf(W1[e * NH + col]);
        A1.s[e + 4] = 0;
        A2.s[e]     = f2bf(W2[(4 * g + e) * NH + col]);
        A2.s[e + 4] = 0;
    }
    f32x4 c1, c2;
#pragma unroll
    for (int r = 0; r < 4; ++r) { c1[r] = b1[4 * g + r]; c2[r] = b2[4 * g + r]; }

    const int idA = batch[wb];
    const int idB = batch[wb + PTW - 1];
    const bool isSlow = (idA != idB);      // wave-uniform

    int bposw = 0x7fffffff;
    if (isSlow) {                          // ~127 waves: locate the boundary
        for (int it = 0; it < PTW / 64; ++it) {
            const int idx = wb + it * 64 + lane;
            const unsigned long long mk = __ballot(batch[idx] != idA);
            if (mk) bposw = min(bposw, wb + it * 64 + (__ffsll((long long)mk) - 1));
        }
    }

    f32x4 accA = {0.f, 0.f, 0.f, 0.f};
    f32x4 accB = {0.f, 0.f, 0.f, 0.f};

    // ---- issue ALL loads up front (8 x float4, independent -> deep MLP) ----
    const float4* gp0 = (const float4*)(pos + (size_t)wb * 3);
    const float4* gp1 = (const float4*)(pos + (size_t)(wb + 256) * 3);
    const float4* gr0 = (const float4*)(refl + wb);
    const float4* gr1 = (const float4*)(refl + wb + 256);
    const float4 qa0 = gp0[3 * lane + 0];
    const float4 qa1 = gp0[3 * lane + 1];
    const float4 qa2 = gp0[3 * lane + 2];
    const float4 ra  = gr0[lane];
    const float4 qb0 = gp1[3 * lane + 0];
    const float4 qb1 = gp1[3 * lane + 1];
    const float4 qb2 = gp1[3 * lane + 2];
    const float4 rb  = gr1[lane];

#pragma unroll
    for (int s = 0; s < SITERS; ++s) {
        const float4 q0 = s ? qb0 : qa0;
        const float4 q1 = s ? qb1 : qa1;
        const float4 q2 = s ? qb2 : qa2;
        const float4 rr = s ? rb  : ra;
        const int    sb = wb + s * 256;
        // lane's 4 points: features f[j][k]
        const float f[4][4] = {{q0.x, q0.y, q0.z, rr.x},
                               {q0.w, q1.x, q1.y, rr.y},
                               {q1.z, q1.w, q2.x, rr.z},
                               {q2.y, q2.z, q2.w, rr.w}};
#pragma unroll
        for (int j = 0; j < 4; ++j) {
            const unsigned F01 = pk2(f[j][0], f[j][1]);
            const unsigned F23 = pk2(f[j][2], f[j][3]);
#pragma unroll
            for (int t = 0; t < 4; ++t) {
                const bool mine = (g == t);
                U8 B;
                B.u[0] = mine ? F01 : 0u;
                B.u[1] = mine ? F23 : 0u;
                B.u[2] = 0u; B.u[3] = 0u;
                f32x4 d = __builtin_amdgcn_mfma_f32_16x16x32_bf16(A1.v, B.v, c1, 0, 0, 0);
                U8 P;
                P.u[0] = pk2(fmaxf(d[0], 0.f), fmaxf(d[1], 0.f));
                P.u[1] = pk2(fmaxf(d[2], 0.f), fmaxf(d[3], 0.f));
                P.u[2] = 0u; P.u[3] = 0u;
                f32x4 h = __builtin_amdgcn_mfma_f32_16x16x32_bf16(A2.v, P.v, c2, 0, 0, 0);
                if (!isSlow) {             // wave-uniform branch
#pragma unroll
                    for (int r = 0; r < 4; ++r) accA[r] = fmaxf(accA[r], h[r]);
                } else {
                    const bool m = (sb + 4 * (16 * t + col) + j) < bposw;
#pragma unroll
                    for (int r = 0; r < 4; ++r) {
                        accA[r] = fmaxf(accA[r], m ? h[r] : 0.f);
                        accB[r] = fmaxf(accB[r], m ? 0.f : h[r]);
                    }
                }
            }
        }
    }

    // ---- wave reduce across the 16 columns ----
#pragma unroll
    for (int mk = 1; mk <= 8; mk <<= 1) {
#pragma unroll
        for (int r = 0; r < 4; ++r) {
            accA[r] = fmaxf(accA[r], __shfl_xor(accA[r], mk));
            accB[r] = fmaxf(accB[r], __shfl_xor(accB[r], mk));
        }
    }
    if (col == 0) {   // lanes 0,16,32,48 hold dims 4g..4g+3
        *reinterpret_cast<float4*>(&lv[wid][0][4 * g]) =
            make_float4(accA[0], accA[1], accA[2], accA[3]);
        *reinterpret_cast<float4*>(&lv[wid][1][4 * g]) =
            make_float4(accB[0], accB[1], accB[2], accB[3]);
    }
    if (lane == 0) {
        li[wid][0] = idA; li[wid][1] = idB;
        lbp[wid]   = isSlow ? bposw : 0x7fffffff;
    }
    __syncthreads();

    // ---- block combine (<=2 segments per 2048-pt block) ----
    if (threadIdx.x < NH) {
        const int d   = threadIdx.x;
        const int ida = li[0][0];
        const int idb = li[WPB - 1][1];
        float mA = 0.f, mB = 0.f;
#pragma unroll
        for (int s = 0; s < WPB; ++s)
#pragma unroll
            for (int hh = 0; hh < 2; ++hh) {
                const float val = lv[s][hh][d];
                if (li[s][hh] == ida) mA = fmaxf(mA, val);
                else                  mB = fmaxf(mB, val);
            }
        pv[(blockIdx.x * 2 + 0) * NH + d] = mA;
        pv[(blockIdx.x * 2 + 1) * NH + d] = mB;
        if (d == 0) {
            pid[blockIdx.x * 2 + 0] = ida;
            pid[blockIdx.x * 2 + 1] = idb;
            int bp = 0x7fffffff;
#pragma unroll
            for (int s = 0; s < WPB; ++s) {
                if (li[s][0] != ida) bp = min(bp, (int)(blockIdx.x * PPB + s * PTW));
                else if (lbp[s] != 0x7fffffff) bp = min(bp, lbp[s]);
            }
            Rec r; r.idA = ida; r.idB = idb; r.bpos = bp;
            recs[blockIdx.x] = r;
        }
    }
}

// ---------------- stage 2: combine partials, compute gate ----------------
__global__ __launch_bounds__(1024) void stage2_kernel(
    const float* __restrict__ pv, const int* __restrict__ pid,
    const float* __restrict__ Wg, const float* __restrict__ bg,
    const float* __restrict__ gum, float* __restrict__ gate)
{
    __shared__ unsigned int sm[NB * NH];   // 1024 floats-as-bits (vals >= 0)
    const int tid = threadIdx.x;
    sm[tid] = 0u;
    __syncthreads();

    for (int i = tid; i < NENT * 4; i += 1024) {
        const float4 v = reinterpret_cast<const float4*>(pv)[i];
        const int e  = i >> 2;
        const int d0 = (i & 3) * 4;
        const int id = pid[e];
        atomicMax(&sm[id * NH + d0 + 0], __float_as_uint(v.x));
        atomicMax(&sm[id * NH + d0 + 1], __float_as_uint(v.y));
        atomicMax(&sm[id * NH + d0 + 2], __float_as_uint(v.z));
        atomicMax(&sm[id * NH + d0 + 3], __float_as_uint(v.w));
    }
    __syncthreads();

    if (tid < NB) {
        float l0 = bg[0] + gum[tid * 2 + 0];
        float l1 = bg[1] + gum[tid * 2 + 1];
#pragma unroll
        for (int k = 0; k < NH; ++k) {
            const float s = __uint_as_float(sm[tid * NH + k]);
            l0 = fmaf(s, Wg[k * 2 + 0], l0);
            l1 = fmaf(s, Wg[k * 2 + 1], l1);
        }
        gate[tid] = 1.f / (1.f + expf(-(l1 - l0)));   // softmax[:,1], TAU=1
    }
}

// ---------------- B: scale via records (no batch reads) ----------------
__global__ __launch_bounds__(256) void scale_kernel(
    const float* __restrict__ refl,
    const Rec*   __restrict__ recs,
    const float* __restrict__ gate,
    float* __restrict__ out)
{
    const Rec rec = recs[blockIdx.x >> 1];     // 2 scale-blocks per A-block
    const float gA = gate[rec.idA];
    const float gB = gate[rec.idB];

    const int p0 = (blockIdx.x * 256 + threadIdx.x) * 4;
    const float4 rr = *reinterpret_cast<const float4*>(refl + p0);
    float4 o;
    o.x = ((p0 + 0) < rec.bpos ? gA : gB) * rr.x;
    o.y = ((p0 + 1) < rec.bpos ? gA : gB) * rr.y;
    o.z = ((p0 + 2) < rec.bpos ? gA : gB) * rr.z;
    o.w = ((p0 + 3) < rec.bpos ? gA : gB) * rr.w;
    *reinterpret_cast<float4*>(out + p0) = o;
}

extern "C" void kernel_launch(void* const* d_in, const int* in_sizes, int n_in,
                              void* d_out, int out_size, void* d_ws, size_t ws_size,
                              hipStream_t stream) {
    const float* pos   = (const float*)d_in[0];
    const float* refl  = (const float*)d_in[1];
    const int*   batch = (const int*)d_in[2];
    const float* gumb  = (const float*)d_in[3];
    const float* W1    = (const float*)d_in[4];
    const float* b1    = (const float*)d_in[5];
    const float* W2    = (const float*)d_in[6];
    const float* b2    = (const float*)d_in[7];
    const float* Wg    = (const float*)d_in[8];
    const float* bg    = (const float*)d_in[9];
    float* out = (float*)d_out;

    // ws layout: pv 256KB | pid 16KB | recs 24KB | gate 256B
    float* pv   = (float*)d_ws;
    int*   pid  = (int*)((char*)d_ws + 262144);
    Rec*   recs = (Rec*)((char*)d_ws + 278528);
    float* gate = (float*)((char*)d_ws + 303104);

    mlp_segmax_kernel<<<NBLK, 256, 0, stream>>>(pos, refl, batch,
                                                W1, b1, W2, b2, pv, pid, recs);
    stage2_kernel<<<1, 1024, 0, stream>>>(pv, pid, Wg, bg, gumb, gate);
    scale_kernel<<<N_PTS / 1024, 256, 0, stream>>>(refl, recs, gate, out);
}

// Round 10
// 40.241 us; speedup vs baseline: 1.4474x; 1.4474x over previous
//
#include <hip/hip_runtime.h>
#include <hip/hip_bf16.h>

// BinaryReflectanceGate: pointwise MLP (4->16->16, relu) -> segment max over
// sorted batch ids [B=64] -> 2-logit gate + gumbel softmax -> scale reflectance.
//
// Round-10: fix r8/r9's latency-bound structure.
//   - fast/slow split at TOP level (straight-line fast path; r8/r9's inner
//     wave-uniform branch fragmented scheduling regions -> serialized chains)
//   - explicit phase ILP per j: 4x MFMA1 -> 4x pack -> 4x MFMA2 (static idx)
//   - rolling distance-1 prefetch of the 4 float4 loads per 256-pt chunk
//   - __launch_bounds__(256,4): <=128 VGPR, 16 waves/CU
//   - NBLK=1024 = exactly 4 blocks/CU resident (no dispatch tail)
//
// MFMA layout facts (HW-verified r4, absmax 0.0039):
//   C/D: col=lane&15, row=(lane>>4)*4+reg. Lane l owns points 4l..4l+3 of each
//   256-pt chunk (pos floats 12l..12l+11 = 3 aligned float4s + refl float4).
//   In MFMA (j,t), lanes with g==t feed their j-th point; column c's point id
//   = sb + 4*(16t+c) + j (closed form, used for straddle select).

#define N_PTS 4194304
#define NB 64
#define NH 16
#define WPB 4                       // waves per block
#define SITERS 4                    // 256-pt chunks per wave
#define PTW (256 * SITERS)          // 1024 points per wave
#define PPB (WPB * PTW)             // 4096 points per block
#define NBLK (N_PTS / PPB)          // 1024 blocks = 4/CU resident
#define NENT (NBLK * 2)             // 2048 partial entries

typedef __attribute__((ext_vector_type(8))) short bf16x8;
typedef __attribute__((ext_vector_type(4))) float f32x4;
union U8 { bf16x8 v; unsigned u[4]; unsigned short s[8]; };

struct Rec { int idA, idB, bpos; };

__device__ __forceinline__ unsigned pk2(float a, float b) {
    float2 t; t.x = a; t.y = b;
    __hip_bfloat162 r = __float22bfloat162_rn(t);
    unsigned u;
    __builtin_memcpy(&u, &r, sizeof(u));
    return u;
}
__device__ __forceinline__ unsigned short f2bf(float x) {   // RNE, setup only
    unsigned u = __float_as_uint(x);
    u = u + 0x7fffu + ((u >> 16) & 1u);
    return (unsigned short)(u >> 16);
}

// One 256-pt chunk: lane's 4 points through both layers, phase-split for ILP.
template<bool SLOW>
__device__ __forceinline__ void do_chunk(
    const float4& q0, const float4& q1, const float4& q2, const float4& rr,
    int sb, int g, int col, int bposw,
    const U8& A1, const U8& A2, const f32x4& c1, const f32x4& c2,
    f32x4& accA, f32x4& accB)
{
    const float f[4][4] = {{q0.x, q0.y, q0.z, rr.x},
                           {q0.w, q1.x, q1.y, rr.y},
                           {q1.z, q1.w, q2.x, rr.z},
                           {q2.y, q2.z, q2.w, rr.w}};
#pragma unroll
    for (int j = 0; j < 4; ++j) {
        const unsigned F01 = pk2(f[j][0], f[j][1]);
        const unsigned F23 = pk2(f[j][2], f[j][3]);
        f32x4 d[4], h[4];                 // static-indexed (fully unrolled)
#pragma unroll
        for (int t = 0; t < 4; ++t) {     // phase 1: 4 independent MFMA1
            const bool mine = (g == t);
            U8 B;
            B.u[0] = mine ? F01 : 0u;
            B.u[1] = mine ? F23 : 0u;
            B.u[2] = 0u; B.u[3] = 0u;
            d[t] = __builtin_amdgcn_mfma_f32_16x16x32_bf16(A1.v, B.v, c1, 0, 0, 0);
        }
#pragma unroll
        for (int t = 0; t < 4; ++t) {     // phase 2+3: pack, 4 MFMA2
            U8 P;
            P.u[0] = pk2(fmaxf(d[t][0], 0.f), fmaxf(d[t][1], 0.f));
            P.u[1] = pk2(fmaxf(d[t][2], 0.f), fmaxf(d[t][3], 0.f));
            P.u[2] = 0u; P.u[3] = 0u;
            h[t] = __builtin_amdgcn_mfma_f32_16x16x32_bf16(A2.v, P.v, c2, 0, 0, 0);
        }
#pragma unroll
        for (int t = 0; t < 4; ++t) {     // phase 4: accumulate
            if (!SLOW) {
#pragma unroll
                for (int r = 0; r < 4; ++r) accA[r] = fmaxf(accA[r], h[t][r]);
            } else {
                const bool m = (sb + 4 * (16 * t + col) + j) < bposw;
#pragma unroll
                for (int r = 0; r < 4; ++r) {
                    accA[r] = fmaxf(accA[r], m ? h[t][r] : 0.f);
                    accB[r] = fmaxf(accB[r], m ? 0.f : h[t][r]);
                }
            }
        }
    }
}

// ---------------- A: MLP + segment-max partials + records ----------------
__global__ __launch_bounds__(256, 4) void mlp_segmax_kernel(
    const float* __restrict__ pos,    // [N,3]
    const float* __restrict__ refl,   // [N]
    const int*   __restrict__ batch,  // [N] sorted
    const float* __restrict__ W1, const float* __restrict__ b1,
    const float* __restrict__ W2, const float* __restrict__ b2,
    float* __restrict__ pv,           // [NENT,16]
    int*   __restrict__ pid,          // [NENT]
    Rec*   __restrict__ recs)         // [NBLK]
{
    __shared__ float lv[WPB][2][NH];
    __shared__ int   li[WPB][2];
    __shared__ int   lbp[WPB];

    const int lane = threadIdx.x & 63;
    const int wid  = threadIdx.x >> 6;
    const int col  = lane & 15;
    const int g    = lane >> 4;
    const int wb   = (blockIdx.x * WPB + wid) * PTW;

    // weight / bias fragments (L1-cached one-time loads)
    U8 A1, A2;
#pragma unroll
    for (int e = 0; e < 4; ++e) {
        A1.s[e]     = f2bf(W1[e * NH + col]);
        A1.s[e + 4] = 0;
        A2.s[e]     = f2bf(W2[(4 * g + e) * NH + col]);
        A2.s[e + 4] = 0;
    }
    f32x4 c1, c2;
#pragma unroll
    for (int r = 0; r < 4; ++r) { c1[r] = b1[4 * g + r]; c2[r] = b2[4 * g + r]; }

    const int idA = batch[wb];
    const int idB = batch[wb + PTW - 1];
    const bool isSlow = (idA != idB);      // wave-uniform

    f32x4 accA = {0.f, 0.f, 0.f, 0.f};
    f32x4 accB = {0.f, 0.f, 0.f, 0.f};

    const float4* gp = (const float4*)(pos + (size_t)wb * 3);
    const float4* gr = (const float4*)(refl + wb);

    float4 q0 = gp[3 * lane + 0];
    float4 q1 = gp[3 * lane + 1];
    float4 q2 = gp[3 * lane + 2];
    float4 rr = gr[lane];

    if (!isSlow) {
        // ---- fast path: straight-line, rolling prefetch ----
#pragma unroll
        for (int s = 0; s < SITERS; ++s) {
            float4 n0, n1, n2, nr;
            if (s + 1 < SITERS) {
                n0 = gp[(s + 1) * 192 + 3 * lane + 0];
                n1 = gp[(s + 1) * 192 + 3 * lane + 1];
                n2 = gp[(s + 1) * 192 + 3 * lane + 2];
                nr = gr[(s + 1) * 64 + lane];
            }
            do_chunk<false>(q0, q1, q2, rr, wb + s * 256, g, col, 0,
                            A1, A2, c1, c2, accA, accB);
            if (s + 1 < SITERS) { q0 = n0; q1 = n1; q2 = n2; rr = nr; }
        }
    } else {
        // ---- slow path (~63 waves): boundary scan, then select-accumulate
        int bposw = 0x7fffffff;
        for (int it = 0; it < PTW / 64; ++it) {
            const int idx = wb + it * 64 + lane;
            const unsigned long long mk = __ballot(batch[idx] != idA);
            if (mk) bposw = min(bposw, wb + it * 64 + (__ffsll((long long)mk) - 1));
        }
#pragma unroll
        for (int s = 0; s < SITERS; ++s) {
            float4 n0, n1, n2, nr;
            if (s + 1 < SITERS) {
                n0 = gp[(s + 1) * 192 + 3 * lane + 0];
                n1 = gp[(s + 1) * 192 + 3 * lane + 1];
                n2 = gp[(s + 1) * 192 + 3 * lane + 2];
                nr = gr[(s + 1) * 64 + lane];
            }
            do_chunk<true>(q0, q1, q2, rr, wb + s * 256, g, col, bposw,
                           A1, A2, c1, c2, accA, accB);
            if (s + 1 < SITERS) { q0 = n0; q1 = n1; q2 = n2; rr = nr; }
        }
        lbp[wid] = bposw;
    }

    // ---- wave reduce across the 16 columns ----
#pragma unroll
    for (int mk = 1; mk <= 8; mk <<= 1) {
#pragma unroll
        for (int r = 0; r < 4; ++r) {
            accA[r] = fmaxf(accA[r], __shfl_xor(accA[r], mk));
            accB[r] = fmaxf(accB[r], __shfl_xor(accB[r], mk));
        }
    }
    if (col == 0) {   // lanes 0,16,32,48 hold dims 4g..4g+3
        *reinterpret_cast<float4*>(&lv[wid][0][4 * g]) =
            make_float4(accA[0], accA[1], accA[2], accA[3]);
        *reinterpret_cast<float4*>(&lv[wid][1][4 * g]) =
            make_float4(accB[0], accB[1], accB[2], accB[3]);
    }
    if (lane == 0) {
        li[wid][0] = idA; li[wid][1] = idB;
        if (!isSlow) lbp[wid] = 0x7fffffff;
    }
    __syncthreads();

    // ---- block combine (<=2 segments per 4096-pt block) ----
    if (threadIdx.x < NH) {
        const int d   = threadIdx.x;
        const int ida = li[0][0];
        const int idb = li[WPB - 1][1];
        float mA = 0.f, mB = 0.f;
#pragma unroll
        for (int s = 0; s < WPB; ++s)
#pragma unroll
            for (int hh = 0; hh < 2; ++hh) {
                const float val = lv[s][hh][d];
                if (li[s][hh] == ida) mA = fmaxf(mA, val);
                else                  mB = fmaxf(mB, val);
            }
        pv[(blockIdx.x * 2 + 0) * NH + d] = mA;
        pv[(blockIdx.x * 2 + 1) * NH + d] = mB;
        if (d == 0) {
            pid[blockIdx.x * 2 + 0] = ida;
            pid[blockIdx.x * 2 + 1] = idb;
            int bp = 0x7fffffff;
#pragma unroll
            for (int s = 0; s < WPB; ++s) {
                if (li[s][0] != ida) bp = min(bp, (int)(blockIdx.x * PPB + s * PTW));
                else if (lbp[s] != 0x7fffffff) bp = min(bp, lbp[s]);
            }
            Rec r; r.idA = ida; r.idB = idb; r.bpos = bp;
            recs[blockIdx.x] = r;
        }
    }
}

// ---------------- stage 2: combine partials, compute gate ----------------
__global__ __launch_bounds__(1024) void stage2_kernel(
    const float* __restrict__ pv, const int* __restrict__ pid,
    const float* __restrict__ Wg, const float* __restrict__ bg,
    const float* __restrict__ gum, float* __restrict__ gate)
{
    __shared__ unsigned int sm[NB * NH];   // 1024 floats-as-bits (vals >= 0)
    const int tid = threadIdx.x;
    sm[tid] = 0u;
    __syncthreads();

    for (int i = tid; i < NENT * 4; i += 1024) {
        const float4 v = reinterpret_cast<const float4*>(pv)[i];
        const int e  = i >> 2;
        const int d0 = (i & 3) * 4;
        const int id = pid[e];
        atomicMax(&sm[id * NH + d0 + 0], __float_as_uint(v.x));
        atomicMax(&sm[id * NH + d0 + 1], __float_as_uint(v.y));
        atomicMax(&sm[id * NH + d0 + 2], __float_as_uint(v.z));
        atomicMax(&sm[id * NH + d0 + 3], __float_as_uint(v.w));
    }
    __syncthreads();

    if (tid < NB) {
        float l0 = bg[0] + gum[tid * 2 + 0];
        float l1 = bg[1] + gum[tid * 2 + 1];
#pragma unroll
        for (int k = 0; k < NH; ++k) {
            const float s = __uint_as_float(sm[tid * NH + k]);
            l0 = fmaf(s, Wg[k * 2 + 0], l0);
            l1 = fmaf(s, Wg[k * 2 + 1], l1);
        }
        gate[tid] = 1.f / (1.f + expf(-(l1 - l0)));   // softmax[:,1], TAU=1
    }
}

// ---------------- B: scale via records (no batch reads) ----------------
__global__ __launch_bounds__(256) void scale_kernel(
    const float* __restrict__ refl,
    const Rec*   __restrict__ recs,
    const float* __restrict__ gate,
    float* __restrict__ out)
{
    const Rec rec = recs[blockIdx.x >> 2];     // 4 scale-blocks per A-block
    const float gA = gate[rec.idA];
    const float gB = gate[rec.idB];

    const int p0 = (blockIdx.x * 256 + threadIdx.x) * 4;
    const float4 rr = *reinterpret_cast<const float4*>(refl + p0);
    float4 o;
    o.x = ((p0 + 0) < rec.bpos ? gA : gB) * rr.x;
    o.y = ((p0 + 1) < rec.bpos ? gA : gB) * rr.y;
    o.z = ((p0 + 2) < rec.bpos ? gA : gB) * rr.z;
    o.w = ((p0 + 3) < rec.bpos ? gA : gB) * rr.w;
    *reinterpret_cast<float4*>(out + p0) = o;
}

extern "C" void kernel_launch(void* const* d_in, const int* in_sizes, int n_in,
                              void* d_out, int out_size, void* d_ws, size_t ws_size,
                              hipStream_t stream) {
    const float* pos   = (const float*)d_in[0];
    const float* refl  = (const float*)d_in[1];
    const int*   batch = (const int*)d_in[2];
    const float* gumb  = (const float*)d_in[3];
    const float* W1    = (const float*)d_in[4];
    const float* b1    = (const float*)d_in[5];
    const float* W2    = (const float*)d_in[6];
    const float* b2    = (const float*)d_in[7];
    const float* Wg    = (const float*)d_in[8];
    const float* bg    = (const float*)d_in[9];
    float* out = (float*)d_out;

    // ws layout: pv 128KB | pid 8KB | recs 12KB | gate 256B
    float* pv   = (float*)d_ws;
    int*   pid  = (int*)((char*)d_ws + 131072);
    Rec*   recs = (Rec*)((char*)d_ws + 139264);
    float* gate = (float*)((char*)d_ws + 151552);

    mlp_segmax_kernel<<<NBLK, 256, 0, stream>>>(pos, refl, batch,
                                                W1, b1, W2, b2, pv, pid, recs);
    stage2_kernel<<<1, 1024, 0, stream>>>(pv, pid, Wg, bg, gumb, gate);
    scale_kernel<<<N_PTS / 1024, 256, 0, stream>>>(refl, recs, gate, out);
}